// Round 10
// baseline (449.959 us; speedup 1.0000x reference)
//
#include <hip/hip_runtime.h>

// Problem constants (LocalitySelfAttention): B=8, N=1024, C=1024, H=16, D=64
#define B_ 8
#define N_ 1024
#define C_ 1024
#define H_ 16
#define D_ 64

typedef __attribute__((ext_vector_type(8))) short short8v;      // 8 bf16 (MFMA frag)
typedef __attribute__((ext_vector_type(4))) float f32x4;        // MFMA acc
typedef __attribute__((ext_vector_type(4))) unsigned short ushort4v;

// fp32 -> bf16 (RNE) and back; hi/lo split captures ~16 mantissa bits
__device__ __forceinline__ unsigned short f2bf_rne(float f) {
    unsigned int u = __float_as_uint(f);
    u += 0x7FFFu + ((u >> 16) & 1u);
    return (unsigned short)(u >> 16);
}
__device__ __forceinline__ float bf2f(unsigned short h) {
    return __uint_as_float(((unsigned int)h) << 16);
}

// async global->LDS DMA, 16B per lane (dest = wave-uniform base + lane*16)
__device__ __forceinline__ void gload16(const void* g, void* l) {
    __builtin_amdgcn_global_load_lds(
        (const __attribute__((address_space(1))) void*)g,
        (__attribute__((address_space(3))) void*)l, 16, 0, 0);
}

// Inverse of LDS byte swizzle f(l) = l ^ ((l>>6 & 7)<<4) (64B rows).
// f flips bit4^=bit6, bit5^=bit7, bit6^=bit8; inverse verified algebraically
// and end-to-end by rounds 7-8 passing.
__device__ __forceinline__ int inv_swz(int p) {
    int l = p ^ ((p >> 2) & 0x40);   // bit6 ^= bit8
    l ^= ((l >> 6) & 3) << 4;        // bit4 ^= bit6, bit5 ^= bit7
    return l;
}

// ---------------------------------------------------------------------------
// x pre-pass: f32 -> hi/lo bf16 elementwise.
// ---------------------------------------------------------------------------
__global__ __launch_bounds__(256) void split_f32(
    const float* __restrict__ in, unsigned short* __restrict__ hi,
    unsigned short* __restrict__ lo, int n4)
{
    for (int i = blockIdx.x * 256 + threadIdx.x; i < n4; i += gridDim.x * 256) {
        const float4 v = *(const float4*)&in[(size_t)i * 4];
        const float f[4] = {v.x, v.y, v.z, v.w};
        ushort4v hv, lv;
#pragma unroll
        for (int j = 0; j < 4; ++j) {
            const unsigned short hu = f2bf_rne(f[j]);
            hv[j] = hu;
            lv[j] = f2bf_rne(f[j] - bf2f(hu));
        }
        *(ushort4v*)&hi[(size_t)i * 4] = hv;
        *(ushort4v*)&lo[(size_t)i * 4] = lv;
    }
}

// ---------------------------------------------------------------------------
// Weight pre-pass: W[K][N] f32 -> T_hi/T_lo[N][K] bf16 (convert + transpose).
// ---------------------------------------------------------------------------
__global__ __launch_bounds__(256) void convert_transpose(
    const float* __restrict__ W, unsigned short* __restrict__ T_hi,
    unsigned short* __restrict__ T_lo, int K, int N)
{
    __shared__ float tile[32][33];
    const int nb = blockIdx.x * 32, kb = blockIdx.y * 32;
    const int t = threadIdx.x;
    {
        const int kr = t >> 3, nq = (t & 7) * 4;
        const float4 v = *(const float4*)&W[(size_t)(kb + kr) * N + nb + nq];
        tile[kr][nq + 0] = v.x; tile[kr][nq + 1] = v.y;
        tile[kr][nq + 2] = v.z; tile[kr][nq + 3] = v.w;
    }
    __syncthreads();
    {
        const int nr = t >> 3, kq = (t & 7) * 4;
        ushort4v hv, lv;
#pragma unroll
        for (int j = 0; j < 4; ++j) {
            const float f = tile[kq + j][nr];
            const unsigned short hu = f2bf_rne(f);
            hv[j] = hu;
            lv[j] = f2bf_rne(f - bf2f(hu));
        }
        const size_t o = (size_t)(nb + nr) * K + kb + kq;
        *(ushort4v*)&T_hi[o] = hv;
        *(ushort4v*)&T_lo[o] = lv;
    }
}

// ---------------------------------------------------------------------------
// GEMM1: 128x384 tile, BK=32, 512 thr = 8 waves (2M x 4N), per-wave 64x96.
// Grid 512 blocks = EXACTLY 2 waves of scheduling per CU. bf16x3 with a
// counted-vmcnt phase pipeline (T3+T4):
//   ph0: vmcnt(4)  bar  issue Ah,Bh(t+1)  read ah,bh   24 MFMA hi*hi
//   ph1: vmcnt(7)  bar  issue Al(t+1)     read al      24 MFMA lo*hi
//   ph2: vmcnt(5)  bar  issue Bl(t+1)     read bl      24 MFMA hi*lo
// Load queue is ALWAYS 8 deep at phase boundaries (never drained to 0 in the
// loop — round 8's one-vmcnt(0)-per-tile measured ~= no pipeline, m218).
// ROUND-9 AUDIT FIXES (offline, after infra timeout):
//  * __launch_bounds__(512, 1): the (512,2) cap forced VGPR<=128 while ~170-200
//    are live -> acc spilled to scratch (this also explains round 8's
//    VGPR_Count=116 < its 128-VGPR acc). LDS=128KB caps at 1 block/CU anyway.
//  * sched_barrier(0) after each s_barrier: s_barrier is IntrNoMem in LLVM, so
//    ds_reads could hoist above it (cross-wave race with DMA landing).
// WAR safety: writes to buffer p issue only after a barrier that post-dates
// every wave's last read of p (verified wave-by-wave).
// ---------------------------------------------------------------------------
__global__ __launch_bounds__(512, 1) void gemm384_8ph(
    const unsigned short* __restrict__ A_hi, const unsigned short* __restrict__ A_lo,
    const unsigned short* __restrict__ Bt_hi, const unsigned short* __restrict__ Bt_lo,
    unsigned short* __restrict__ C_hi, unsigned short* __restrict__ C_lo,
    int M, int N, int K)
{
    __shared__ short AhS[2][4096];    // 8 KB per buffer: 128 rows x 32 k
    __shared__ short AlS[2][4096];
    __shared__ short BhS[2][12288];   // 24 KB per buffer: 384 rows x 32 k
    __shared__ short BlS[2][12288];   // total 128 KB
    char* const AhB = (char*)AhS;
    char* const AlB = (char*)AlS;
    char* const BhB = (char*)BhS;
    char* const BlB = (char*)BlS;

    const int tid = threadIdx.x;
    const int lane = tid & 63;
    const int w = tid >> 6;             // 0..7
    const int wm = w >> 2, wn = w & 3;  // 2M x 4N
    const int bm = blockIdx.y * 128, bn = blockIdx.x * 384;
    const int l15 = lane & 15, l4 = lane >> 4;
    const int wA = w * 1024;            // wave-uniform dest byte offset

    // staging sources: linear LDS byte p <- global element inv_swz(p)
    const int lA = inv_swz(wA + lane * 16);
    const unsigned short* srcAh =
        A_hi + (size_t)(bm + (lA >> 6)) * K + ((lA >> 4) & 3) * 8;
    const unsigned short* srcAl =
        A_lo + (size_t)(bm + (lA >> 6)) * K + ((lA >> 4) & 3) * 8;
    const unsigned short* srcBh[3];
    const unsigned short* srcBl[3];
#pragma unroll
    for (int i = 0; i < 3; ++i) {
        const int l = inv_swz(i * 8192 + wA + lane * 16);
        srcBh[i] = Bt_hi + (size_t)(bn + (l >> 6)) * K + ((l >> 4) & 3) * 8;
        srcBl[i] = Bt_lo + (size_t)(bn + (l >> 6)) * K + ((l >> 4) & 3) * 8;
    }

    f32x4 acc[4][6];
#pragma unroll
    for (int m = 0; m < 4; ++m)
#pragma unroll
        for (int n = 0; n < 6; ++n) acc[m][n] = (f32x4){0.f, 0.f, 0.f, 0.f};

    const int nt = K / 32;   // 32

    // prologue: issue ALL of tile 0 in consumption order -> queue depth 8
    gload16(srcAh, AhB + wA);
    gload16(srcBh[0], BhB + 0 * 8192 + wA);
    gload16(srcBh[1], BhB + 1 * 8192 + wA);
    gload16(srcBh[2], BhB + 2 * 8192 + wA);
    gload16(srcAl, AlB + wA);
    gload16(srcBl[0], BlB + 0 * 8192 + wA);
    gload16(srcBl[1], BlB + 1 * 8192 + wA);
    gload16(srcBl[2], BlB + 2 * 8192 + wA);

    for (int t = 0; t < nt; ++t) {
        const int cb = t & 1;
        const int nb2 = cb ^ 1;
        const int cA = cb * 8192, nA = nb2 * 8192;     // A buffer byte offsets
        const int cB = cb * 24576, nB = nb2 * 24576;   // B buffer byte offsets
        const int knx = ((t + 1) & (nt - 1)) * 32;     // wraps on last tile
        short8v ah[4], bh[6], al[4], bl[6];

        // ---------------- phase 0: hi*hi ----------------
        asm volatile("s_waitcnt vmcnt(4)" ::: "memory");  // Ah,Bh(t) landed
        __builtin_amdgcn_s_barrier();
        __builtin_amdgcn_sched_barrier(0);
        gload16(srcAh + knx, AhB + nA + wA);
        gload16(srcBh[0] + knx, BhB + nB + 0 * 8192 + wA);
        gload16(srcBh[1] + knx, BhB + nB + 1 * 8192 + wA);
        gload16(srcBh[2] + knx, BhB + nB + 2 * 8192 + wA);
#pragma unroll
        for (int m = 0; m < 4; ++m) {
            const int row = wm * 64 + m * 16 + l15;
            ah[m] = *(const short8v*)(AhB + cA +
                ((row * 64 + l4 * 16) ^ ((row & 7) << 4)));
        }
#pragma unroll
        for (int n = 0; n < 6; ++n) {
            const int row = wn * 96 + n * 16 + l15;
            bh[n] = *(const short8v*)(BhB + cB +
                ((row * 64 + l4 * 16) ^ ((row & 7) << 4)));
        }
        __builtin_amdgcn_s_setprio(1);
#pragma unroll
        for (int m = 0; m < 4; ++m)
#pragma unroll
            for (int n = 0; n < 6; ++n)
                acc[m][n] = __builtin_amdgcn_mfma_f32_16x16x32_bf16(
                    ah[m], bh[n], acc[m][n], 0, 0, 0);
        __builtin_amdgcn_s_setprio(0);

        // ---------------- phase 1: lo*hi ----------------
        asm volatile("s_waitcnt vmcnt(7)" ::: "memory");  // Al(t) landed
        __builtin_amdgcn_s_barrier();
        __builtin_amdgcn_sched_barrier(0);
        gload16(srcAl + knx, AlB + nA + wA);
#pragma unroll
        for (int m = 0; m < 4; ++m) {
            const int row = wm * 64 + m * 16 + l15;
            al[m] = *(const short8v*)(AlB + cA +
                ((row * 64 + l4 * 16) ^ ((row & 7) << 4)));
        }
        __builtin_amdgcn_s_setprio(1);
#pragma unroll
        for (int m = 0; m < 4; ++m)
#pragma unroll
            for (int n = 0; n < 6; ++n)
                acc[m][n] = __builtin_amdgcn_mfma_f32_16x16x32_bf16(
                    al[m], bh[n], acc[m][n], 0, 0, 0);
        __builtin_amdgcn_s_setprio(0);

        // ---------------- phase 2: hi*lo ----------------
        asm volatile("s_waitcnt vmcnt(5)" ::: "memory");  // Bl(t) landed
        __builtin_amdgcn_s_barrier();
        __builtin_amdgcn_sched_barrier(0);
        gload16(srcBl[0] + knx, BlB + nB + 0 * 8192 + wA);
        gload16(srcBl[1] + knx, BlB + nB + 1 * 8192 + wA);
        gload16(srcBl[2] + knx, BlB + nB + 2 * 8192 + wA);
#pragma unroll
        for (int n = 0; n < 6; ++n) {
            const int row = wn * 96 + n * 16 + l15;
            bl[n] = *(const short8v*)(BlB + cB +
                ((row * 64 + l4 * 16) ^ ((row & 7) << 4)));
        }
        __builtin_amdgcn_s_setprio(1);
#pragma unroll
        for (int m = 0; m < 4; ++m)
#pragma unroll
            for (int n = 0; n < 6; ++n)
                acc[m][n] = __builtin_amdgcn_mfma_f32_16x16x32_bf16(
                    ah[m], bl[n], acc[m][n], 0, 0, 0);
        __builtin_amdgcn_s_setprio(0);
    }
    asm volatile("s_waitcnt vmcnt(0)" ::: "memory");  // retire dangling prefetch

    // ---- epilogue: C/D layout col=lane&15, row=4*(lane>>4)+reg; hi/lo out ----
#pragma unroll
    for (int n = 0; n < 6; ++n) {
        const int col = bn + wn * 96 + n * 16 + l15;
#pragma unroll
        for (int m = 0; m < 4; ++m) {
            const int row0 = bm + wm * 64 + m * 16 + l4 * 4;
#pragma unroll
            for (int r = 0; r < 4; ++r) {
                const size_t idx = (size_t)(row0 + r) * N + col;
                const float f = acc[m][n][r];
                const unsigned short hu = f2bf_rne(f);
                C_hi[idx] = hu;
                C_lo[idx] = f2bf_rne(f - bf2f(hu));
            }
        }
    }
}

// ---------------------------------------------------------------------------
// GEMM2: 128x128 bf16x3 (validated rounds 7-8, unchanged). f32 + bias out.
// ---------------------------------------------------------------------------
__global__ __launch_bounds__(256, 2) void gemm_split_f32out(
    const unsigned short* __restrict__ A_hi, const unsigned short* __restrict__ A_lo,
    const unsigned short* __restrict__ Bt_hi, const unsigned short* __restrict__ Bt_lo,
    const float* __restrict__ bias, float* __restrict__ Cf,
    int M, int N, int K)
{
    __shared__ short As_hi[128 * 32], As_lo[128 * 32];
    __shared__ short Bs_hi[128 * 32], Bs_lo[128 * 32];

    const int tid = threadIdx.x;
    const int lane = tid & 63;
    const int w = tid >> 6;
    const int wm = w >> 1, wn = w & 1;
    const int bm = blockIdx.y * 128, bn = blockIdx.x * 128;
    const int l15 = lane & 15, l4 = lane >> 4;

    const unsigned short *pAh[2], *pAl[2], *pBh[2], *pBl[2];
    char *dAh[2], *dAl[2], *dBh[2], *dBl[2];
#pragma unroll
    for (int i = 0; i < 2; ++i) {
        const int p = w * 2048 + i * 1024 + lane * 16;
        const int l = inv_swz(p);
        const int row = l >> 6, kg = (l >> 4) & 3;
        pAh[i] = A_hi + (size_t)(bm + row) * K + kg * 8;
        pAl[i] = A_lo + (size_t)(bm + row) * K + kg * 8;
        pBh[i] = Bt_hi + (size_t)(bn + row) * K + kg * 8;
        pBl[i] = Bt_lo + (size_t)(bn + row) * K + kg * 8;
        dAh[i] = (char*)As_hi + w * 2048 + i * 1024;
        dAl[i] = (char*)As_lo + w * 2048 + i * 1024;
        dBh[i] = (char*)Bs_hi + w * 2048 + i * 1024;
        dBl[i] = (char*)Bs_lo + w * 2048 + i * 1024;
    }

    f32x4 acc[4][4];
#pragma unroll
    for (int m = 0; m < 4; ++m)
#pragma unroll
        for (int n = 0; n < 4; ++n) acc[m][n] = (f32x4){0.f, 0.f, 0.f, 0.f};

    for (int k0 = 0; k0 < K; k0 += 32) {
#pragma unroll
        for (int i = 0; i < 2; ++i) {
            gload16(pAh[i] + k0, dAh[i]);
            gload16(pAl[i] + k0, dAl[i]);
            gload16(pBh[i] + k0, dBh[i]);
            gload16(pBl[i] + k0, dBl[i]);
        }
        __syncthreads();

        short8v ah[4], al[4], bh[4], bl[4];
#pragma unroll
        for (int m = 0; m < 4; ++m) {
            const int row = wm * 64 + m * 16 + l15;
            const int off = (row * 64 + l4 * 16) ^ ((row & 7) << 4);
            ah[m] = *(const short8v*)((char*)As_hi + off);
            al[m] = *(const short8v*)((char*)As_lo + off);
        }
#pragma unroll
        for (int n = 0; n < 4; ++n) {
            const int row = wn * 64 + n * 16 + l15;
            const int off = (row * 64 + l4 * 16) ^ ((row & 7) << 4);
            bh[n] = *(const short8v*)((char*)Bs_hi + off);
            bl[n] = *(const short8v*)((char*)Bs_lo + off);
        }

#pragma unroll
        for (int m = 0; m < 4; ++m)
#pragma unroll
            for (int n = 0; n < 4; ++n) {
                acc[m][n] = __builtin_amdgcn_mfma_f32_16x16x32_bf16(
                    ah[m], bh[n], acc[m][n], 0, 0, 0);
                acc[m][n] = __builtin_amdgcn_mfma_f32_16x16x32_bf16(
                    ah[m], bl[n], acc[m][n], 0, 0, 0);
                acc[m][n] = __builtin_amdgcn_mfma_f32_16x16x32_bf16(
                    al[m], bh[n], acc[m][n], 0, 0, 0);
            }
        __syncthreads();
    }

#pragma unroll
    for (int n = 0; n < 4; ++n) {
        const int col = bn + wn * 64 + n * 16 + l15;
        const float bv = bias ? bias[col] : 0.f;
#pragma unroll
        for (int m = 0; m < 4; ++m) {
            const int row0 = bm + wm * 64 + m * 16 + l4 * 4;
#pragma unroll
            for (int r = 0; r < 4; ++r)
                Cf[(size_t)(row0 + r) * N + col] = acc[m][n][r] + bv;
        }
    }
}

// ---------------------------------------------------------------------------
// MFMA flash attention (validated rounds 6-8, unchanged).
// ---------------------------------------------------------------------------
__global__ __launch_bounds__(256, 2) void attn_mfma(
    const unsigned short* __restrict__ qkv_hi,
    const unsigned short* __restrict__ qkv_lo,
    const float* __restrict__ scale,
    unsigned short* __restrict__ attn_hi, unsigned short* __restrict__ attn_lo)
{
    constexpr int C3 = 3 * C_;

    __shared__ short Kh[64 * 64];   // K hi [key][d], byte^=(key&7)<<4
    __shared__ short Kl[64 * 64];   // K lo
    __shared__ short Vt[64 * 64];   // V^T hi [d][key], byte^=(d&7)<<4

    const int bid = blockIdx.x;
    const int rt  = 15 - (bid >> 7);
    const int hb  = bid & 127;
    const int h   = hb & 15;
    const int b   = hb >> 4;

    const int tid  = threadIdx.x;
    const int w    = tid >> 6;
    const int lane = tid & 63;
    const int l15  = lane & 15;
    const int g    = lane >> 4;

    const float sc = scale[h];

    short8v qh[2], ql[2];
    {
        const size_t qoff =
            ((size_t)(b * N_ + rt * 64 + w * 16 + l15)) * C3 + h * D_;
#pragma unroll
        for (int t = 0; t < 2; ++t) {
            qh[t] = *(const short8v*)&qkv_hi[qoff + t * 32 + g * 8];
            ql[t] = *(const short8v*)&qkv_lo[qoff + t * 32 + g * 8];
        }
    }

    f32x4 accO[4];
#pragma unroll
    for (int n = 0; n < 4; ++n) accO[n] = (f32x4){0.f, 0.f, 0.f, 0.f};
    float m_old = -1e30f, l_old = 0.f;

    for (int jt = 0; jt <= rt; ++jt) {
        __syncthreads();

#pragma unroll
        for (int it = 0; it < 2; ++it) {
            const int u2  = tid + 256 * it;
            const int row = u2 >> 3;
            const int dq8 = u2 & 7;
            const size_t base =
                ((size_t)(b * N_ + jt * 64 + row)) * C3 + C_ + h * D_ + dq8 * 8;
            const int kbyte = (row * 128 + dq8 * 16) ^ ((row & 7) << 4);
            *(short8v*)((char*)Kh + kbyte) = *(const short8v*)&qkv_hi[base];
            *(short8v*)((char*)Kl + kbyte) = *(const short8v*)&qkv_lo[base];
        }
#pragma unroll
        for (int vt = 0; vt < 4; ++vt) {
            const int u2  = tid + 256 * vt;
            const int row = u2 >> 4;
            const int dq  = (u2 & 15) * 4;
            const size_t base =
                ((size_t)(b * N_ + jt * 64 + row)) * C3 + 2 * C_ + h * D_ + dq;
            const unsigned long long v8 = *(const unsigned long long*)&qkv_hi[base];
            unsigned short ov[4];
            ov[0] = (unsigned short)v8;
            ov[1] = (unsigned short)(v8 >> 16);
            ov[2] = (unsigned short)(v8 >> 32);
            ov[3] = (unsigned short)(v8 >> 48);
            int pv[4];
#pragma unroll
            for (int j = 0; j < 4; ++j) pv[j] = __shfl_xor((int)ov[j], 16, 64);
            const int row2 = row & ~1;
            const int odd  = row & 1;
#pragma unroll
            for (int s2 = 0; s2 < 2; ++s2) {
                const int i = odd * 2 + s2;
                const int d = dq + i;
                const unsigned int fe = odd ? (unsigned short)pv[i] : ov[i];
                const unsigned int fo = odd ? ov[i] : (unsigned short)pv[i];
                const unsigned int pack = fe | (fo << 16);
                const int vbyte = (d * 128 + row2 * 2) ^ ((d & 7) << 4);
                *(unsigned int*)((char*)Vt + vbyte) = pack;
            }
        }
        __syncthreads();

        const int kbmax = (jt == rt) ? w : 3;
        f32x4 accS[4];
#pragma unroll
        for (int kb = 0; kb < 4; ++kb) accS[kb] = (f32x4){0.f, 0.f, 0.f, 0.f};
        for (int kb = 0; kb <= kbmax; ++kb) {
#pragma unroll
            for (int t = 0; t < 2; ++t) {
                const int kbyte =
                    ((16 * kb + l15) * 128 + t * 64 + g * 16) ^ ((l15 & 7) << 4);
                const short8v kh = *(const short8v*)((const char*)Kh + kbyte);
                const short8v kl = *(const short8v*)((const char*)Kl + kbyte);
                accS[kb] = __builtin_amdgcn_mfma_f32_16x16x32_bf16(
                    kh, qh[t], accS[kb], 0, 0, 0);
                accS[kb] = __builtin_amdgcn_mfma_f32_16x16x32_bf16(
                    kh, ql[t], accS[kb], 0, 0, 0);
                accS[kb] = __builtin_amdgcn_mfma_f32_16x16x32_bf16(
                    kl, qh[t], accS[kb], 0, 0, 0);
            }
        }

        float p[16];
        float tmax = -1e30f;
#pragma unroll
        for (int kb = 0; kb < 4; ++kb) {
#pragma unroll
            for (int r = 0; r < 4; ++r) {
                float s = accS[kb][r] * sc;
                bool allow = (kb <= kbmax);
                if (jt == rt && kb == w) allow = allow && ((4 * g + r) < l15);
                s = allow ? s : -1e30f;
                p[kb * 4 + r] = s;
                tmax = fmaxf(tmax, s);
            }
        }
        tmax = fmaxf(tmax, __shfl_xor(tmax, 16, 64));
        tmax = fmaxf(tmax, __shfl_xor(tmax, 32, 64));
        const float m_new = fmaxf(m_old, tmax);
        const float alpha = __expf(m_old - m_new);
        float lsum = 0.f;
#pragma unroll
        for (int i = 0; i < 16; ++i) {
            const float pe = (p[i] > -1e29f) ? __expf(p[i] - m_new) : 0.f;
            p[i] = pe;
            lsum += pe;
        }
        lsum += __shfl_xor(lsum, 16, 64);
        lsum += __shfl_xor(lsum, 32, 64);
        l_old = alpha * l_old + lsum;
        m_old = m_new;

        unsigned int pk[4][2];
#pragma unroll
        for (int kb = 0; kb < 4; ++kb) {
            pk[kb][0] = (unsigned int)f2bf_rne(p[kb * 4 + 0]) |
                        ((unsigned int)f2bf_rne(p[kb * 4 + 1]) << 16);
            pk[kb][1] = (unsigned int)f2bf_rne(p[kb * 4 + 2]) |
                        ((unsigned int)f2bf_rne(p[kb * 4 + 3]) << 16);
        }

        float ar[4];
#pragma unroll
        for (int r = 0; r < 4; ++r) ar[r] = __shfl(alpha, 4 * g + r, 64);
#pragma unroll
        for (int n = 0; n < 4; ++n)
#pragma unroll
            for (int r = 0; r < 4; ++r) accO[n][r] *= ar[r];

        const int s0 = l15 + 16 * ((2 * g) & 3);
        const int s1 = l15 + 16 * ((2 * g + 1) & 3);
        const bool lowg = (g < 2);
#pragma unroll
        for (int t = 0; t < 2; ++t) {
            const int a0 = __shfl((int)pk[2 * t][0], s0, 64);
            const int a1 = __shfl((int)pk[2 * t][1], s0, 64);
            const int b0 = __shfl((int)pk[2 * t + 1][0], s0, 64);
            const int b1 = __shfl((int)pk[2 * t + 1][1], s0, 64);
            const int c0 = __shfl((int)pk[2 * t][0], s1, 64);
            const int c1 = __shfl((int)pk[2 * t][1], s1, 64);
            const int d0 = __shfl((int)pk[2 * t + 1][0], s1, 64);
            const int d1 = __shfl((int)pk[2 * t + 1][1], s1, 64);
            union { short8v v; int u[4]; } A;
            A.u[0] = lowg ? a0 : b0;
            A.u[1] = lowg ? a1 : b1;
            A.u[2] = lowg ? c0 : d0;
            A.u[3] = lowg ? c1 : d1;
#pragma unroll
            for (int n = 0; n < 4; ++n) {
                const int vbyte =
                    ((16 * n + l15) * 128 + t * 64 + g * 16) ^ ((l15 & 7) << 4);
                const short8v vt = *(const short8v*)((const char*)Vt + vbyte);
                accO[n] = __builtin_amdgcn_mfma_f32_16x16x32_bf16(
                    A.v, vt, accO[n], 0, 0, 0);
            }
        }
    }

    float linv[4];
#pragma unroll
    for (int r = 0; r < 4; ++r) {
        const float lr = __shfl(l_old, 4 * g + r, 64);
        linv[r] = (lr > 0.f) ? 1.f / lr : 0.f;
    }
#pragma unroll
    for (int n = 0; n < 4; ++n) {
#pragma unroll
        for (int r = 0; r < 4; ++r) {
            const float f = accO[n][r] * linv[r];
            const unsigned short hu = f2bf_rne(f);
            const unsigned short lu = f2bf_rne(f - bf2f(hu));
            const size_t idx =
                ((size_t)(b * N_ + rt * 64 + w * 16 + 4 * g + r)) * C_ +
                h * 64 + 16 * n + l15;
            attn_hi[idx] = hu;
            attn_lo[idx] = lu;
        }
    }
}

// ---------------------------------------------------------------------------
// Memory plan (unchanged; ws <= 128 MB, d_out doubles as x hi/lo scratch).
// ---------------------------------------------------------------------------
extern "C" void kernel_launch(void* const* d_in, const int* in_sizes, int n_in,
                              void* d_out, int out_size, void* d_ws, size_t ws_size,
                              hipStream_t stream) {
    (void)in_sizes; (void)n_in; (void)out_size; (void)ws_size;
    const float* x      = (const float*)d_in[0];
    const float* w_qkv  = (const float*)d_in[1];
    const float* scale  = (const float*)d_in[2];
    const float* w_out  = (const float*)d_in[3];
    const float* b_out  = (const float*)d_in[4];
    float* out = (float*)d_out;

    char* ws = (char*)d_ws;
    unsigned short* x_hi = (unsigned short*)d_out;              // 16 MB
    unsigned short* x_lo = x_hi + (size_t)B_ * N_ * C_;         // 16 MB
    unsigned short* qkv_hi = (unsigned short*)ws;               // 48 MB
    unsigned short* qkv_lo = (unsigned short*)(ws + ((size_t)48 << 20));
    unsigned short* woutT_hi = (unsigned short*)ws;             // 2 MB (after attn)
    unsigned short* woutT_lo = (unsigned short*)(ws + ((size_t)2 << 20));
    unsigned short* wqkvT_hi = (unsigned short*)(ws + ((size_t)96 << 20));
    unsigned short* wqkvT_lo = (unsigned short*)(ws + ((size_t)102 << 20));
    unsigned short* attn_hi  = (unsigned short*)(ws + ((size_t)96 << 20));
    unsigned short* attn_lo  = (unsigned short*)(ws + ((size_t)112 << 20));

    const int M = B_ * N_;

    split_f32<<<2048, 256, 0, stream>>>(x, x_hi, x_lo, M * C_ / 4);

    convert_transpose<<<dim3(3 * C_ / 32, C_ / 32), 256, 0, stream>>>(
        w_qkv, wqkvT_hi, wqkvT_lo, C_, 3 * C_);

    gemm384_8ph<<<dim3(3 * C_ / 384, M / 128), 512, 0, stream>>>(
        x_hi, x_lo, wqkvT_hi, wqkvT_lo, qkv_hi, qkv_lo, M, 3 * C_, C_);

    attn_mfma<<<2048, 256, 0, stream>>>(qkv_hi, qkv_lo, scale, attn_hi, attn_lo);

    convert_transpose<<<dim3(C_ / 32, C_ / 32), 256, 0, stream>>>(
        w_out, woutT_hi, woutT_lo, C_, C_);

    gemm_split_f32out<<<dim3(C_ / 128, M / 128), 256, 0, stream>>>(
        attn_hi, attn_lo, woutT_hi, woutT_lo, b_out, out, M, C_, C_);
}